// Round 13
// baseline (1472.421 us; speedup 1.0000x reference)
//
#include <hip/hip_runtime.h>
#include <cstddef>

#define DEVFN __device__ __forceinline__

constexpr int N0   = 2712;             // 768+640+704+600
constexpr int MAXL = 768;
constexpr int NBAT = 4;
constexpr int E    = 512;
constexpr int F    = 1024;
constexpr int HID  = 160;
constexpr int WSZ  = 16;               // window length
constexpr int NY   = 2 * WSZ * HID;    // 5120: [u | d] fused Y width
constexpr int NY1  = 6144;             // level-1: [u|d (5120) | DH1K(512) | DH1V(512)]
constexpr int DH1KC = 5120;
constexpr int DH1VC = 5632;
constexpr int XSTR = 7680;             // XO row: [kv0(1024)|KH0(512)|VH0(512)|qh(512)|Y0(5120)]
constexpr int YC0  = 2560;             // Y0 column base within XO
constexpr size_t NOFF = (size_t)-1;

// ---------------- static device scratch pool (offsets in floats) ----------------
constexpr size_t oXF    = 0;
constexpr size_t oXO    = oXF    + (size_t)N0*E;
constexpr size_t oEU0   = oXO    + (size_t)N0*XSTR;
constexpr size_t oDAT1  = oEU0   + (size_t)N0;
constexpr size_t oEU1   = oDAT1  + (size_t)N0*F;
constexpr size_t oDAT2  = oEU1   + (size_t)N0;
constexpr size_t oBH0K  = oDAT2  + (size_t)N0*F;
constexpr size_t oBH0V  = oBH0K  + (size_t)15*E;
constexpr size_t oDH2K  = oBH0V  + (size_t)15*E;
constexpr size_t oDH2V  = oDH2K  + (size_t)N0*E;
constexpr size_t oCTX   = oDH2V  + (size_t)N0*E;
constexpr size_t oY2    = oCTX   + (size_t)N0*E;
constexpr size_t oEUS0  = oY2    + (size_t)N0*E;
constexpr size_t oEUS1  = oEUS0  + (size_t)N0;
constexpr size_t oSEL0  = oEUS1  + (size_t)N0;
constexpr size_t oTM0   = oSEL0  + (size_t)N0;
constexpr size_t oSEL1  = oTM0   + (size_t)N0;
constexpr size_t oTM1   = oSEL1  + (size_t)N0;
constexpr size_t oB0    = oTM1   + (size_t)N0;
constexpr size_t oB1    = oB0    + 8;
constexpr size_t oB2    = oB1    + 8;
constexpr size_t oWOP   = oB2    + 8;
constexpr size_t oBOP   = oWOP   + (size_t)E*E;
constexpr size_t oWX    = oBOP   + E;              // 512 x 7680
constexpr size_t oXB    = oWX    + (size_t)E*XSTR; // 7680 bias
constexpr size_t oBD0   = oXB    + XSTR;           // F x NY
constexpr size_t oBD1   = oBD0   + (size_t)F*NY;   // F x NY1  ([BD1 | wk-pad | wv-pad])
constexpr size_t oBUFY0 = oBD1   + (size_t)F*NY1;
constexpr size_t oBUFY1 = oBUFY0 + (size_t)15*NY;
constexpr size_t oYB    = oBUFY1 + (size_t)15*NY;  // Y1X (N0 x NY1); also W0Y split-K scratch
constexpr size_t oP1    = oYB    + (size_t)N0*NY1; // Y1X split-K z=1 partial
constexpr size_t oEND   = oP1    + (size_t)N0*NY1;

__device__ float g_pool[oEND];

DEVFN float geluf(float x) {
    return 0.5f * x * (1.0f + erff(x / 1.41421356237309504880f));
}

// ---------------- tiny init ----------------
__global__ void k_init() {
    if (threadIdx.x == 0) {
        int* b = (int*)(g_pool + oB0);
        b[0] = 0; b[1] = 768; b[2] = 1408; b[3] = 2112; b[4] = N0;
    }
}

// ---------------- x (B,768,E) -> x_flat (N0,E) ----------------
__global__ __launch_bounds__(256) void k_xflat(const float* __restrict__ x) {
    int idx = blockIdx.x * 256 + threadIdx.x;
    if (idx >= N0 * E) return;
    int d = idx & (E - 1);
    int g = idx >> 9;
    int s = (g >= 768) + (g >= 1408) + (g >= 2112);
    const int st[4] = {0, 768, 1408, 2112};
    int qp = g - st[s];
    g_pool[oXF + idx] = x[((size_t)s * MAXL + qp) * E + d];
}

// ---------------- w1 (16384,160) pairs -> BD0 (1024, 5120) ----------------
__global__ __launch_bounds__(256) void k_reshape(
    const float* __restrict__ uw, const float* __restrict__ dw, size_t bdOff)
{
    int idx = blockIdx.x * 256 + threadIdx.x;
    if (idx >= F * NY) return;
    int col = idx % NY;
    int f = idx / NY;
    const float* src = (col < NY / 2) ? uw : dw;
    int rem = (col < NY / 2) ? col : col - NY / 2;
    int j = rem / HID, n = rem % HID;
    g_pool[bdOff + idx] = src[((size_t)j * F + f) * HID + n];
}

// ---------------- level-1 B: [BD1 (5120) | wk-pad (512) | wv-pad (512)] (1024 x 6144) ----------------
__global__ __launch_bounds__(256) void k_bd1x(
    const float* __restrict__ uw, const float* __restrict__ dw,
    const float* __restrict__ wk, const float* __restrict__ wv)
{
    int idx = blockIdx.x * 256 + threadIdx.x;
    if (idx >= F * NY1) return;
    int col = idx % NY1;
    int f = idx / NY1;
    float v;
    if (col < NY) {
        const float* src = (col < NY / 2) ? uw : dw;
        int rem = (col < NY / 2) ? col : col - NY / 2;
        int j = rem / HID, n = rem % HID;
        v = src[((size_t)j * F + f) * HID + n];
    } else if (col < DH1VC) {
        int m = col - DH1KC;
        v = (f < E) ? wk[(size_t)f * E + m] : 0.0f;
    } else {
        int m = col - DH1VC;
        v = (f >= E) ? wv[(size_t)(f - E) * E + m] : 0.0f;
    }
    g_pool[oBD1 + idx] = v;
}

// ---------------- kv_w -> WX[:, 0:1024] ----------------
__global__ __launch_bounds__(256) void k_copymat(
    const float* __restrict__ src, size_t dstOff, int rows, int cols, int lds, int ldd)
{
    int idx = blockIdx.x * 256 + threadIdx.x;
    if (idx >= rows * cols) return;
    int r = idx / cols, c = idx % cols;
    g_pool[dstOff + (size_t)r * ldd + c] = src[(size_t)r * lds + c];
}

// ---------------- fused bias prep: XB[0:2560] + BOP[512] ----------------
__global__ __launch_bounds__(256) void k_prepvec(
    const float* __restrict__ kv_b, const float* __restrict__ q_b, const float* __restrict__ out_b,
    const float* __restrict__ wk, const float* __restrict__ bk,
    const float* __restrict__ wv, const float* __restrict__ bv,
    const float* __restrict__ wq, const float* __restrict__ bq,
    const float* __restrict__ proj_w, const float* __restrict__ proj_b)
{
    int idx = blockIdx.x * 256 + threadIdx.x;
    if (idx >= 3072) return;
    if (idx < 1024) { g_pool[oXB + idx] = kv_b[idx]; return; }
    const float* vec; const float* W; const float* add; int n; size_t dst;
    if (idx < 1536)      { n = idx - 1024; vec = kv_b;     W = wk;     add = bk;     dst = oXB + idx; }
    else if (idx < 2048) { n = idx - 1536; vec = kv_b + E; W = wv;     add = bv;     dst = oXB + idx; }
    else if (idx < 2560) { n = idx - 2048; vec = q_b;      W = wq;     add = bq;     dst = oXB + idx; }
    else                 { n = idx - 2560; vec = out_b;    W = proj_w; add = proj_b; dst = oBOP + n; }
    float s = add[n];
    for (int k = 0; k < E; ++k) s = fmaf(vec[k], W[(size_t)k * E + n], s);
    g_pool[dst] = s;
}

// ---------------- cvec = kv_b @ BD0 -> XB[2560:7680] ----------------
__global__ __launch_bounds__(256) void k_cvec(const float* __restrict__ kv_b) {
    int n = blockIdx.x * 256 + threadIdx.x;
    if (n >= NY) return;
    const float* BD = g_pool + oBD0;
    float s = 0.0f;
    for (int k = 0; k < F; ++k) s = fmaf(kv_b[k], BD[(size_t)k * NY + n], s);
    g_pool[oXB + YC0 + n] = s;
}

// ---------------- 64x64 f32 GEMM body (4x4 micro, 256 threads) ----------------
DEVFN void gemm64_body(
    const float* __restrict__ A, int lda,
    const float* __restrict__ B, int ldb,
    const float* __restrict__ bias,
    float* __restrict__ C, int ldc,
    int mval, int row0, int col0, int K, int N)
{
    __shared__ __align__(16) float As[32][68];
    __shared__ __align__(16) float Bs[32][64];

    int tid = threadIdx.x;
    float acc[4][4] = {};
    int tx = tid & 15, ty = tid >> 4;

    for (int k0 = 0; k0 < K; k0 += 32) {
        #pragma unroll
        for (int l = 0; l < 8; ++l) {
            int idx = tid + l * 256;
            int kk = idx & 31, m = idx >> 5;
            int r = row0 + m;
            float v = 0.0f;
            if (r < mval) v = A[(size_t)r * lda + k0 + kk];
            As[kk][m] = v;
        }
        #pragma unroll
        for (int l = 0; l < 8; ++l) {
            int idx = tid + l * 256;
            int n = idx & 63, kk = idx >> 6;
            int col = col0 + n;
            float v = 0.0f;
            if (col < N) v = B[(size_t)(k0 + kk) * ldb + col];
            Bs[kk][n] = v;
        }
        __syncthreads();
        #pragma unroll
        for (int kk = 0; kk < 32; ++kk) {
            float4 a4 = *(const float4*)&As[kk][ty * 4];
            float4 b4 = *(const float4*)&Bs[kk][tx * 4];
            float av[4] = {a4.x, a4.y, a4.z, a4.w};
            float bv[4] = {b4.x, b4.y, b4.z, b4.w};
            #pragma unroll
            for (int i = 0; i < 4; ++i)
                #pragma unroll
                for (int jn = 0; jn < 4; ++jn)
                    acc[i][jn] = fmaf(av[i], bv[jn], acc[i][jn]);
        }
        __syncthreads();
    }

    #pragma unroll
    for (int i = 0; i < 4; ++i) {
        int r = row0 + ty * 4 + i;
        if (r >= mval) continue;
        #pragma unroll
        for (int jn = 0; jn < 4; ++jn) {
            int col = col0 + tx * 4 + jn;
            if (col < N)
                C[(size_t)r * ldc + col] = acc[i][jn] + (bias ? bias[col] : 0.0f);
        }
    }
}

// generic pool-based 64-tile GEMM (y2 projection)
__global__ __launch_bounds__(256) void k_pgemm(
    size_t Aoff, int lda, size_t Boff, int ldb, size_t biasOff,
    size_t Coff, int ldc, int M, size_t mdevOff, int K, int N)
{
    int mval = (mdevOff == NOFF) ? M : *(const int*)(g_pool + mdevOff);
    int row0 = blockIdx.x * 64, col0 = blockIdx.y * 64;
    if (row0 >= mval) return;
    gemm64_body(g_pool + Aoff, lda, g_pool + Boff, ldb,
                (biasOff == NOFF) ? nullptr : g_pool + biasOff,
                g_pool + Coff, ldc, mval, row0, col0, K, N);
}

// z-batched weight-prep: {kv_w_k@wk, kv_w_v@wv, q_w@wq, out_w@proj_w}
__global__ __launch_bounds__(256) void k_wprep(
    const float* __restrict__ kv_w, const float* __restrict__ q_w, const float* __restrict__ out_w,
    const float* __restrict__ wk, const float* __restrict__ wv,
    const float* __restrict__ wq, const float* __restrict__ proj_w)
{
    int z = blockIdx.z;
    const float* A; int lda; const float* B; float* C; int ldc;
    if (z == 0)      { A = kv_w;     lda = F; B = wk;     C = g_pool + oWX + 1024; ldc = XSTR; }
    else if (z == 1) { A = kv_w + E; lda = F; B = wv;     C = g_pool + oWX + 1536; ldc = XSTR; }
    else if (z == 2) { A = q_w;      lda = E; B = wq;     C = g_pool + oWX + 2048; ldc = XSTR; }
    else             { A = out_w;    lda = E; B = proj_w; C = g_pool + oWOP;       ldc = E;    }
    gemm64_body(A, lda, B, E, nullptr, C, ldc, E, blockIdx.x * 64, blockIdx.y * 64, E, E);
}

// z-batched bufY: {buf0@BD0, buf1@BD1 (first 5120 cols of BD1X)}
__global__ __launch_bounds__(256) void k_bufy(
    const float* __restrict__ buf0, const float* __restrict__ buf1)
{
    int z = blockIdx.z;
    const float* A = z ? buf1 : buf0;
    const float* B = g_pool + (z ? oBD1 : oBD0);
    int ldb = z ? NY1 : NY;
    float* C = g_pool + (z ? oBUFY1 : oBUFY0);
    gemm64_body(A, F, B, ldb, nullptr, C, NY, 15, 0, blockIdx.y * 64, F, NY);
}

// z-batched buffer K/V projections: {buf0_k@wk+bk, buf0_v@wv+bv}
__global__ __launch_bounds__(256) void k_bh(
    const float* __restrict__ buf0,
    const float* __restrict__ wk, const float* __restrict__ bk,
    const float* __restrict__ wv, const float* __restrict__ bv)
{
    int z = blockIdx.z;
    const float* A = buf0 + (size_t)z * E;
    const float* B = z ? wv : wk;
    const float* bias = z ? bv : bk;
    float* C = g_pool + (z ? oBH0V : oBH0K);
    gemm64_body(A, F, B, E, bias, C, E, 15, 0, blockIdx.y * 64, E, E);
}

// ---------------- big f32 GEMM: 128x128 tile, 256 threads, 8x8 micro, reg-dbuf ----------------
DEVFN void fma_8x8(const float4& a0, const float4& a1, const float4& b0, const float4& b1,
                   float2 (&acc)[8][4])
{
    float av[8] = {a0.x, a0.y, a0.z, a0.w, a1.x, a1.y, a1.z, a1.w};
    float2 bv[4] = {make_float2(b0.x, b0.y), make_float2(b0.z, b0.w),
                    make_float2(b1.x, b1.y), make_float2(b1.z, b1.w)};
    #pragma unroll
    for (int i = 0; i < 8; ++i) {
        #pragma unroll
        for (int q = 0; q < 4; ++q) {
            acc[i][q].x = fmaf(av[i], bv[q].x, acc[i][q].x);
            acc[i][q].y = fmaf(av[i], bv[q].y, acc[i][q].y);
        }
    }
}

DEVFN void gemm128_body(
    const float* __restrict__ A, int lda,
    const float* __restrict__ B, int ldb,
    const float* __restrict__ bias,
    float* __restrict__ C, int ldc,
    int mval, int row0, int col0, int K)
{
    __shared__ __align__(16) float As[16][132];   // transposed: As[k][m]
    __shared__ __align__(16) float Bs[16][132];

    int tid = threadIdx.x;
    int tx = tid & 15, ty = tid >> 4;             // tx: col quad, ty: row octet
    float2 acc[8][4] = {};

    int ar = tid >> 1, akq = (tid & 1) * 8;       // A staging: row, k-offset
    int bk = tid >> 4, bnq = (tid & 15) * 8;      // B staging: k, n-offset

    for (int k0 = 0; k0 < K; k0 += 16) {
        {
            float4 v0 = make_float4(0.f, 0.f, 0.f, 0.f), v1 = v0;
            int rr = row0 + ar;
            if (rr < mval) {
                v0 = *(const float4*)&A[(size_t)rr * lda + k0 + akq];
                v1 = *(const float4*)&A[(size_t)rr * lda + k0 + akq + 4];
            }
            As[akq + 0][ar] = v0.x; As[akq + 1][ar] = v0.y;
            As[akq + 2][ar] = v0.z; As[akq + 3][ar] = v0.w;
            As[akq + 4][ar] = v1.x; As[akq + 5][ar] = v1.y;
            As[akq + 6][ar] = v1.z; As[akq + 7][ar] = v1.w;
        }
        {
            const float* bp = &B[(size_t)(k0 + bk) * ldb + col0 + bnq];
            *(float4*)&Bs[bk][bnq]     = *(const float4*)&bp[0];
            *(float4*)&Bs[bk][bnq + 4] = *(const float4*)&bp[4];
        }
        __syncthreads();

        float4 a0A = *(const float4*)&As[0][ty * 8];
        float4 a1A = *(const float4*)&As[0][ty * 8 + 4];
        float4 b0A = *(const float4*)&Bs[0][tx * 4];
        float4 b1A = *(const float4*)&Bs[0][64 + tx * 4];
        #pragma unroll
        for (int kk = 0; kk < 16; kk += 2) {
            float4 a0B = *(const float4*)&As[kk + 1][ty * 8];
            float4 a1B = *(const float4*)&As[kk + 1][ty * 8 + 4];
            float4 b0B = *(const float4*)&Bs[kk + 1][tx * 4];
            float4 b1B = *(const float4*)&Bs[kk + 1][64 + tx * 4];
            fma_8x8(a0A, a1A, b0A, b1A, acc);
            if (kk + 2 < 16) {
                a0A = *(const float4*)&As[kk + 2][ty * 8];
                a1A = *(const float4*)&As[kk + 2][ty * 8 + 4];
                b0A = *(const float4*)&Bs[kk + 2][tx * 4];
                b1A = *(const float4*)&Bs[kk + 2][64 + tx * 4];
            }
            fma_8x8(a0B, a1B, b0B, b1B, acc);
        }
        __syncthreads();
    }

    #pragma unroll
    for (int i = 0; i < 8; ++i) {
        int r = row0 + ty * 8 + i;
        if (r >= mval) continue;
        float o0[4], o1[4];
        o0[0] = acc[i][0].x; o0[1] = acc[i][0].y; o0[2] = acc[i][1].x; o0[3] = acc[i][1].y;
        o1[0] = acc[i][2].x; o1[1] = acc[i][2].y; o1[2] = acc[i][3].x; o1[3] = acc[i][3].y;
        if (bias) {
            #pragma unroll
            for (int jn = 0; jn < 4; ++jn) {
                o0[jn] += bias[col0 + tx * 4 + jn];
                o1[jn] += bias[col0 + 64 + tx * 4 + jn];
            }
        }
        *(float4*)&C[(size_t)r * ldc + col0 + tx * 4]      = *(float4*)&o0[0];
        *(float4*)&C[(size_t)r * ldc + col0 + 64 + tx * 4] = *(float4*)&o1[0];
    }
}

__global__ __launch_bounds__(256) void k_tgemm(
    size_t Aoff, int lda, size_t Boff, int ldb, size_t biasOff,
    size_t Coff, int ldc, int M, size_t mdevOff, int K)
{
    int mval = (mdevOff == NOFF) ? M : *(const int*)(g_pool + mdevOff);
    int row0 = blockIdx.x * 128, col0 = blockIdx.y * 128;
    if (row0 >= mval) return;
    gemm128_body(g_pool + Aoff, lda, g_pool + Boff, ldb,
                 (biasOff == NOFF) ? nullptr : g_pool + biasOff,
                 g_pool + Coff, ldc, mval, row0, col0, K);
}

// ---------------- big f32 GEMM: 256x128 tile, 256 threads, 16x8 micro ----------------
// A-frag reads are 4-address broadcasts (conflict-free); LDS/FMA 25-50% below gemm128.
// Use ONLY on unmasked large-grid GEMMs (needs >= ~2.5 active blocks/CU).
__global__ __launch_bounds__(256) void k_tg256(
    size_t Aoff, int lda, size_t Boff, int ldb, size_t biasOff,
    size_t Coff, int ldc, int M, size_t mdevOff, int K)
{
    int mval = (mdevOff == NOFF) ? M : *(const int*)(g_pool + mdevOff);
    int row0 = blockIdx.x * 256, col0 = blockIdx.y * 128;
    if (row0 >= mval) return;

    const float* A = g_pool + Aoff;
    const float* B = g_pool + Boff;
    const float* bias = (biasOff == NOFF) ? nullptr : g_pool + biasOff;
    float* C = g_pool + Coff;

    __shared__ __align__(16) float As[256 * 20];   // row-major, stride 20 words
    __shared__ __align__(16) float Bs[16][132];

    int tid = threadIdx.x;
    int tx = tid & 15, ty = tid >> 4;              // tx: col quad 0..15, ty: row phase 0..15
    float acc[16][8] = {};

    for (int k0 = 0; k0 < K; k0 += 16) {
        {
            int rr = row0 + tid;
            float4 v0 = make_float4(0.f,0.f,0.f,0.f), v1 = v0, v2 = v0, v3 = v0;
            if (rr < mval) {
                const float* ap = &A[(size_t)rr * lda + k0];
                v0 = *(const float4*)&ap[0];
                v1 = *(const float4*)&ap[4];
                v2 = *(const float4*)&ap[8];
                v3 = *(const float4*)&ap[12];
            }
            float* as = &As[tid * 20];
            *(float4*)&as[0]  = v0;
            *(float4*)&as[4]  = v1;
            *(float4*)&as[8]  = v2;
            *(float4*)&as[12] = v3;
        }
        #pragma unroll
        for (int l = 0; l < 2; ++l) {
            int idx = tid + l * 256;
            int k = idx >> 5, nq = (idx & 31) * 4;
            *(float4*)&Bs[k][nq] = *(const float4*)&B[(size_t)(k0 + k) * ldb + col0 + nq];
        }
        __syncthreads();

        #pragma unroll
        for (int kq = 0; kq < 4; ++kq) {
            float4 b0[4], b1[4];
            #pragma unroll
            for (int dk = 0; dk < 4; ++dk) {
                b0[dk] = *(const float4*)&Bs[kq * 4 + dk][tx * 4];
                b1[dk] = *(const float4*)&Bs[kq * 4 + dk][64 + tx * 4];
            }
            #pragma unroll
            for (int i = 0; i < 16; ++i) {
                float4 aq = *(const float4*)&As[(ty + 16 * i) * 20 + kq * 4];
                float av[4] = {aq.x, aq.y, aq.z, aq.w};
                #pragma unroll
                for (int dk = 0; dk < 4; ++dk) {
                    acc[i][0] = fmaf(av[dk], b0[dk].x, acc[i][0]);
                    acc[i][1] = fmaf(av[dk], b0[dk].y, acc[i][1]);
                    acc[i][2] = fmaf(av[dk], b0[dk].z, acc[i][2]);
                    acc[i][3] = fmaf(av[dk], b0[dk].w, acc[i][3]);
                    acc[i][4] = fmaf(av[dk], b1[dk].x, acc[i][4]);
                    acc[i][5] = fmaf(av[dk], b1[dk].y, acc[i][5]);
                    acc[i][6] = fmaf(av[dk], b1[dk].z, acc[i][6]);
                    acc[i][7] = fmaf(av[dk], b1[dk].w, acc[i][7]);
                }
            }
        }
        __syncthreads();
    }

    #pragma unroll
    for (int i = 0; i < 16; ++i) {
        int r = row0 + ty + 16 * i;
        if (r >= mval) continue;
        float o0[4], o1[4];
        #pragma unroll
        for (int jn = 0; jn < 4; ++jn) {
            o0[jn] = acc[i][jn]     + (bias ? bias[col0 + tx * 4 + jn]      : 0.0f);
            o1[jn] = acc[i][jn + 4] + (bias ? bias[col0 + 64 + tx * 4 + jn] : 0.0f);
        }
        *(float4*)&C[(size_t)r * ldc + col0 + tx * 4]      = *(float4*)&o0[0];
        *(float4*)&C[(size_t)r * ldc + col0 + 64 + tx * 4] = *(float4*)&o1[0];
    }
}

// W0Y = kv_w @ BD0, split-K 4 ways (partials in oYB scratch)
__global__ __launch_bounds__(256) void k_wy(const float* __restrict__ kv_w) {
    int z = blockIdx.z;
    const float* A = kv_w + z * 256;                       // lda=F, K-slice [z*256, z*256+256)
    const float* B = g_pool + oBD0 + (size_t)z * 256 * NY;
    float* C = g_pool + oYB + (size_t)z * E * NY;
    gemm128_body(A, F, B, NY, nullptr, C, NY, E, blockIdx.x * 128, blockIdx.y * 128, 256);
}

__global__ __launch_bounds__(256) void k_wyred() {
    int idx = blockIdx.x * 256 + threadIdx.x;
    if (idx >= E * NY) return;
    int r = idx / NY, c = idx % NY;
    const float* p = g_pool + oYB;
    float s = ((p[idx] + p[(size_t)E * NY + idx]) + p[(size_t)2 * E * NY + idx]) + p[(size_t)3 * E * NY + idx];
    g_pool[oWX + (size_t)r * XSTR + YC0 + c] = s;
}

// Y1X split-K=2: z=0 -> YB (k<512), z=1 -> P1 (k>=512); one dispatch for 2x concurrency
__global__ __launch_bounds__(256) void k_y1x() {
    int mval = *(const int*)(g_pool + oB1 + 4);
    int row0 = blockIdx.x * 128, col0 = blockIdx.y * 128;
    if (row0 >= mval) return;
    int z = blockIdx.z;
    const float* A = g_pool + oDAT1 + (size_t)z * 512;          // lda = F
    const float* B = g_pool + oBD1 + (size_t)z * 512 * NY1;
    float* C = g_pool + (z ? oP1 : oYB);
    gemm128_body(A, F, B, NY1, nullptr, C, NY1, mval, row0, col0, 512);
}

// reduce: YB += P1 (rows < n1), float4 grid-stride; order = lowK + highK
__global__ __launch_bounds__(256) void k_y1red() {
    int mval = *(const int*)(g_pool + oB1 + 4);
    size_t total = (size_t)mval * NY1 / 4;
    float4* yb = (float4*)(g_pool + oYB);
    const float4* p1 = (const float4*)(g_pool + oP1);
    for (size_t i = (size_t)blockIdx.x * 256 + threadIdx.x; i < total; i += (size_t)gridDim.x * 256) {
        float4 a = yb[i], b = p1[i];
        a.x += b.x; a.y += b.y; a.z += b.z; a.w += b.w;
        yb[i] = a;
    }
}

// z-batched DH2 projections (64-tile): {dat2_k@wk, dat2_v@wv}
__global__ __launch_bounds__(256) void k_zgemm(
    const float* __restrict__ wk, const float* __restrict__ wv)
{
    int z = blockIdx.z;
    int mval = *(const int*)(g_pool + oB2 + 4);
    int row0 = blockIdx.x * 64, col0 = blockIdx.y * 64;
    if (row0 >= mval) return;
    const float* A = g_pool + oDAT2 + (size_t)z * E;
    const float* B = z ? wv : wk;
    float* C = g_pool + (z ? oDH2V : oDH2K);
    gemm64_body(A, F, B, E, nullptr, C, E, mval, row0, col0, E, E);
}

// ---------------- fused shift-sum(u) + eu ----------------
__global__ void k_huev(
    size_t boundsOff, size_t yOff, int yStr, size_t bufYOff,
    const float* __restrict__ b1, const float* __restrict__ w2, const float* __restrict__ b2,
    size_t euOff, size_t mdevOff, int M)
{
    int i = blockIdx.x;
    int mval = (mdevOff == NOFF) ? M : *(const int*)(g_pool + mdevOff);
    if (i >= mval) return;
    int n = threadIdx.x;

    __shared__ float t[HID];
    const int* bounds = (const int*)(g_pool + boundsOff);
    int b1i = bounds[1], b2i = bounds[2], b3i = bounds[3];
    int s = (i >= b1i) + (i >= b2i) + (i >= b3i);
    int st = (s == 0) ? 0 : ((s == 1) ? b1i : ((s == 2) ? b2i : b3i));
    int qp = i - st;

    const float* Y = g_pool + yOff;
    const float* bufY = g_pool + bufYOff;

    if (n < HID) {
        float acc = b1[n];
        #pragma unroll
        for (int j = 0; j < WSZ; ++j) {
            int sp = qp - j;
            const float* row = (sp >= 0) ? &Y[(size_t)(i - j) * yStr]
                                         : &bufY[(size_t)(15 + sp) * NY];
            acc += row[j * HID + n];
        }
        t[n] = geluf(acc) * w2[n];
    }
    __syncthreads();
    if (n == 0) {
        float v = b2[0];
        for (int k = 0; k < HID; ++k) v += t[k];
        v = (v > 0.0f) ? v : expm1f(v);
        g_pool[euOff + i] = v + 1.0f;
    }
}

// ---------------- selection scan: serial f32 prefix (bit-exact) + parallel rest ----------------
__global__ __launch_bounds__(256) void k_select(
    size_t euOff, size_t boundsOff, int win,
    size_t selOff, size_t tmOff, size_t euSelOff, size_t boundsNextOff)
{
    __shared__ __align__(16) float se[N0];
    __shared__ __align__(16) float run[N0];
    __shared__ int sFlag[N0];
    __shared__ int sSum[256];
    __shared__ float sCz[NBAT];
    __shared__ int sEc[NBAT];
    __shared__ int sB[5];

    int tid = threadIdx.x;
    const int* bounds = (const int*)(g_pool + boundsOff);
    if (tid < 5) sB[tid] = bounds[tid];
    __syncthreads();
    int N = sB[4];
    for (int i = tid; i < N; i += 256) se[i] = g_pool[euOff + i];
    __syncthreads();

    if (tid == 0) {
        float r = 0.0f;
        int g = 0;
        for (; g + 8 <= N; g += 8) {
            float4 a = *(const float4*)&se[g];
            float4 b4 = *(const float4*)&se[g + 4];
            r += a.x;  run[g]     = r;
            r += a.y;  run[g + 1] = r;
            r += a.z;  run[g + 2] = r;
            r += a.w;  run[g + 3] = r;
            r += b4.x; run[g + 4] = r;
            r += b4.y; run[g + 5] = r;
            r += b4.z; run[g + 6] = r;
            r += b4.w; run[g + 7] = r;
        }
        for (; g < N; ++g) { r += se[g]; run[g] = r; }
        float e0 = run[sB[1] - 1], e1 = run[sB[2] - 1], e2 = run[sB[3] - 1];
        float su0 = e0;
        float su1 = e2 - e1;
        float su2 = run[sB[4] - 1] - e2;
        sCz[0] = 0.0f;
        sCz[1] = su0;
        sCz[2] = su0 + su1;
        sCz[3] = (su0 + su1) + su2;
    }
    __syncthreads();

    for (int g = tid; g < N; g += 256) {
        int seg = (g >= sB[1]) + (g >= sB[2]) + (g >= sB[3]);
        int st = (seg == 0) ? 0 : sB[seg];
        int qp1 = g - st + 1;
        float r2 = run[g] - sCz[seg];
        bool seld = (se[g] > r2 / (float)qp1) || (qp1 <= win);
        sFlag[g] = seld ? 1 : 0;
    }
    __syncthreads();

    int CH = (N + 255) >> 8;
    int lo = tid * CH, hi = min(lo + CH, N);
    {
        int s = 0;
        for (int g = lo; g < hi; ++g) s += sFlag[g];
        sSum[tid] = s;
    }
    __syncthreads();
    if (tid == 0) {
        int acc = 0;
        for (int t = 0; t < 256; ++t) { int v = sSum[t]; sSum[t] = acc; acc += v; }
    }
    __syncthreads();

    int* sel = (int*)(g_pool + selOff);
    int* tm  = (int*)(g_pool + tmOff);
    float* eus = g_pool + euSelOff;
    int* bn  = (int*)(g_pool + boundsNextOff);

    int csel0 = sFlag[0];
    {
        int csel = sSum[tid];
        for (int g = lo; g < hi; ++g) {
            csel += sFlag[g];
            tm[g] = csel - csel0;
            if (sFlag[g]) { sel[csel - 1] = g; eus[csel - 1] = se[g]; }
            #pragma unroll
            for (int s = 0; s < NBAT; ++s)
                if (g == sB[s + 1] - 1) sEc[s] = csel;
        }
    }
    __syncthreads();
    if (tid == 0) {
        bn[0] = 0; bn[1] = sEc[0]; bn[2] = sEc[1]; bn[3] = sEc[2]; bn[4] = sEc[3];
    }
}

// ---------------- fused shift-sum(d) + r-softmax + dat (float4 f-loop) ----------------
__global__ __launch_bounds__(256) void k_rdat(
    size_t boundsOff, size_t yOff, int yStr, size_t bufYOff,
    const float* __restrict__ b1, const float* __restrict__ w2, const float* __restrict__ b2,
    size_t selOff, size_t mdevOff,
    size_t srcOff, int srcStr, const float* __restrict__ buf,
    size_t datOff)
{
    int i = blockIdx.x;
    if (i >= *(const int*)(g_pool + mdevOff)) return;
    const float* src = g_pool + srcOff;
    const int* bounds = (const int*)(g_pool + boundsOff);
    const int* sel = (const int*)(g_pool + selOff);
    float* dat = g_pool + datOff;

    __shared__ float gh[HID];
    __shared__ float sv[WSZ];
    __shared__ float r[WSZ];
    __shared__ int sG, sQp;

    int tid = threadIdx.x;
    if (tid == 0) {
        int g = sel[i];
        int b1i = bounds[1], b2i = bounds[2], b3i = bounds[3];
        int s = (g >= b1i) + (g >= b2i) + (g >= b3i);
        int st = (s == 0) ? 0 : ((s == 1) ? b1i : ((s == 2) ? b2i : b3i));
        sG = g; sQp = g - st;
    }
    __syncthreads();
    int g = sG, qp = sQp;

    if (tid < HID) {
        const float* Y = g_pool + yOff;
        const float* bufY = g_pool + bufYOff;
        float acc = b1[tid];
        #pragma unroll
        for (int j = 0; j < WSZ; ++j) {
            int sp = qp - j;
            const float* row = (sp >= 0) ? &Y[(size_t)(g - j) * yStr]
                                         : &bufY[(size_t)(15 + sp) * NY];
            acc += row[NY / 2 + j * HID + tid];
        }
        gh[tid] = geluf(acc);
    }
    __syncthreads();
    if (tid < WSZ) {
        float acc = 0.0f;
        for (int k = 0; k < HID; ++k) acc += gh[k] * w2[k * WSZ + tid];
        sv[tid] = acc + b2[tid];
    }
    __syncthreads();
    if (tid == 0) {
        float m = sv[0];
        for (int t = 1; t < WSZ; ++t) m = fmaxf(m, sv[t]);
        float sum = 0.0f;
        for (int t = 0; t < WSZ; ++t) { float e = expf(sv[t] - m); r[t] = e; sum += e; }
        for (int t = 0; t < WSZ; ++t) r[t] = r[t] / sum;
    }
    __syncthreads();
    {
        int f0 = tid * 4;            // 256 threads x 4 = 1024 = F
        float4 acc = make_float4(0.f, 0.f, 0.f, 0.f);
        #pragma unroll
        for (int j = 0; j < WSZ; ++j) {
            int sp = qp - j;
            const float* row = (sp >= 0) ? &src[(size_t)(g - j) * srcStr]
                                         : &buf[(size_t)(15 + sp) * F];
            float4 v = *(const float4*)&row[f0];
            float rj = r[j];
            acc.x = fmaf(rj, v.x, acc.x);
            acc.y = fmaf(rj, v.y, acc.y);
            acc.z = fmaf(rj, v.z, acc.z);
            acc.w = fmaf(rj, v.w, acc.w);
        }
        *(float4*)&dat[(size_t)i * F + f0] = acc;
    }
}

// ---------------- fused attention over 48 gathered kv slots ----------------
__global__ __launch_bounds__(512) void k_attn(
    const float* __restrict__ bk, const float* __restrict__ bv)
{
    int g = blockIdx.x;
    const float* XO   = g_pool + oXO;
    const float* BH0k = g_pool + oBH0K;
    const float* BH0v = g_pool + oBH0V;
    const float* Y1X  = g_pool + oYB;     // DH1K/DH1V live at cols 5120/5632, stride NY1
    const float* DH2k = g_pool + oDH2K;
    const float* DH2v = g_pool + oDH2V;
    const float* eus0 = g_pool + oEUS0;
    const float* eus1 = g_pool + oEUS1;
    const int* tm0 = (const int*)(g_pool + oTM0);
    const int* tm1 = (const int*)(g_pool + oTM1);
    const int* bounds1 = (const int*)(g_pool + oB1);
    const int* bounds2 = (const int*)(g_pool + oB2);

    __shared__ const float* sK[48];
    __shared__ const float* sV[48];
    __shared__ float sScale[48];
    __shared__ __align__(16) float sQ[E], sBk[E], sBv[E];
    __shared__ float sc[48][8];

    int tid = threadIdx.x;
    sQ[tid]  = XO[(size_t)g * XSTR + 2048 + tid];
    sBk[tid] = bk[tid];
    sBv[tid] = bv[tid];

    if (tid < 48) {
        int s = tid;
        const float *pK = nullptr, *pV = nullptr;
        float scl = 0.0f;
        if (s < 16) {
            int s0 = (g >= 768) + (g >= 1408) + (g >= 2112);
            const int st0[4] = {0, 768, 1408, 2112};
            int sp = (g - st0[s0]) - s;
            if (sp >= 0) { pK = XO + (size_t)(g - s) * XSTR + 1024; pV = XO + (size_t)(g - s) * XSTR + 1536; }
            else         { pK = BH0k + (size_t)(15 + sp) * E; pV = BH0v + (size_t)(15 + sp) * E; }
            scl = 1.0f;
        } else if (s < 32) {
            int j = s - 16;
            int i1 = tm0[g];
            int b1 = bounds1[1], b2 = bounds1[2], b3 = bounds1[3];
            int sg = (i1 >= b1) + (i1 >= b2) + (i1 >= b3);
            int st = (sg == 0) ? 0 : ((sg == 1) ? b1 : ((sg == 2) ? b2 : b3));
            int sp = (i1 - st) - j;
            if (sp >= 0) {
                pK = Y1X + (size_t)(i1 - j) * NY1 + DH1KC;
                pV = Y1X + (size_t)(i1 - j) * NY1 + DH1VC;
                scl = eus0[i1 - j];
            }
        } else {
            int j = s - 32;
            int i1 = tm0[g];
            int i2 = tm1[i1];
            int b1 = bounds2[1], b2 = bounds2[2], b3 = bounds2[3];
            int sg = (i2 >= b1) + (i2 >= b2) + (i2 >= b3);
            int st = (sg == 0) ? 0 : ((sg == 1) ? b1 : ((sg == 2) ? b2 : b3));
            int sp = (i2 - st) - j;
            if (sp >= 0) { pK = DH2k + (size_t)(i2 - j) * E; pV = DH2v + (size_t)(i2 - j) * E; scl = eus1[i2 - j]; }
        }
        sK[s] = pK; sV[s] = pV; sScale[s] = scl;
    }
    __syncthreads();

    if (tid < 384) {
        int s = tid >> 3, h = tid & 7;
        const float* bp = sK[s];
        float scl = sScale[s];
        float acc = 0.0f;
        int d0 = h * 64;
        if (s < 16) {
            for (int d = 0; d < 64; d += 4) {
                float4 qv = *(const float4*)&sQ[d0 + d];
                float4 kv4 = *(const float4*)&bp[d0 + d];
                acc += qv.x * kv4.x; acc += qv.y * kv4.y;
                acc += qv.z * kv4.z; acc += qv.w * kv4.w;
            }
        } else if (bp) {
            for (int d = 0; d < 64; d += 4) {
                float4 qv = *(const float4*)&sQ[d0 + d];
                float4 kv4 = *(const float4*)&bp[d0 + d];
                float4 bb = *(const float4*)&sBk[d0 + d];
                acc += qv.x * (bb.x + scl * kv4.x); acc += qv.y * (bb.y + scl * kv4.y);
                acc += qv.z * (bb.z + scl * kv4.z); acc += qv.w * (bb.w + scl * kv4.w);
            }
        } else {
            for (int d = 0; d < 64; d += 4) {
                float4 qv = *(const float4*)&sQ[d0 + d];
                float4 bb = *(const float4*)&sBk[d0 + d];
                acc += qv.x * bb.x; acc += qv.y * bb.y;
                acc += qv.z * bb.z; acc += qv.w * bb.w;
            }
        }
        sc[s][h] = acc * 0.125f;   // / sqrt(64)
    }
    __syncthreads();

    if (tid < 8) {
        int h = tid;
        float m = sc[0][h];
        for (int s = 1; s < 48; ++s) m = fmaxf(m, sc[s][h]);
        float sum = 0.0f;
        for (int s = 0; s < 48; ++s) { float e = expf(sc[s][h] - m); sc[s][h] = e; sum += e; }
        for (int s = 0; s < 48; ++s) sc[s][h] = sc[s][h] / sum;
    }
    __syncthreads();

    {
        int d = tid, h = d >> 6;
        float acc = 0.0f;
        for (int s = 0; s < 48; ++s) {
            const float* bp = sV[s];
            float vv;
            if (s < 16) vv = bp[d];
            else        vv = sBv[d] + (bp ? sScale[s] * bp[d] : 0.0f);
            acc = fmaf(sc[s][h], vv, acc);
        }
        g_pool[oCTX + (size_t)g * E + d] = acc;
    }
}

// ---------------- y2 -> out (B, 768, E) with zero padding ----------------
__global__ __launch_bounds__(256) void k_scatter(float* __restrict__ out) {
    int idx = blockIdx.x * 256 + threadIdx.x;
    if (idx >= NBAT * MAXL * E) return;
    int d = idx & (E - 1);
    int rest = idx >> 9;
    int p = rest % MAXL, bb = rest / MAXL;
    const int st[4] = {0, 768, 1408, 2112};
    const int ln[4] = {768, 640, 704, 600};
    out[idx] = (p < ln[bb]) ? g_pool[oY2 + (size_t)(st[bb] + p) * E + d] : 0.0f;
}

// ================================================================================
extern "C" void kernel_launch(void* const* d_in, const int* in_sizes, int n_in,
                              void* d_out, int out_size, void* d_ws, size_t ws_size,
                              hipStream_t stream)
{
    (void)in_sizes; (void)n_in; (void)d_ws; (void)ws_size; (void)out_size;

    const float* x      = (const float*)d_in[0];
    const float* kv_w   = (const float*)d_in[2];
    const float* kv_b   = (const float*)d_in[3];
    const float* q_w    = (const float*)d_in[4];
    const float* q_b    = (const float*)d_in[5];
    const float* proj_w = (const float*)d_in[6];
    const float* proj_b = (const float*)d_in[7];
    const float* buf0   = (const float*)d_in[8];
    const float* buf1   = (const float*)d_in[9];
    const float* d0_w1  = (const float*)d_in[11];
    const float* d0_b1  = (const float*)d_in[12];
    const float* d0_w2  = (const float*)d_in[13];
    const float* d0_b2  = (const float*)d_in[14];
    const float* u0_w1  = (const float*)d_in[15];
    const float* u0_b1  = (const float*)d_in[16];
    const float* u0_w2  = (const float*)d_in[17];
    const float* u0_b2  = (const float*)d_in[18];
    const float* d1_w1  = (const float*)d_in[19];
    const float* d1_b1  = (const float*)d_in[20];
    const float* d1_w2  = (const float*)d_in[21];
    const float* d1_b2  = (const float*)d_in[22];
    const float* u1_w1  = (const float*)d_in[23];
    const float* u1_b1  = (const float*)d_in[24];
    const float* u1_w2  = (const float*)d_in[25];
    const float* u1_b2  = (const float*)d_in[26];
    const float* wq     = (const float*)d_in[27];
    const float* bq     = (const float*)d_in[28];
    const float* wk     = (const float*)d_in[29];
    const float* bk     = (const float*)d_in[30];
    const float* wv     = (const float*)d_in[31];
    const float* bv     = (const float*)d_in[32];
    const float* out_w  = (const float*)d_in[33];
    const float* out_b  = (const float*)d_in[34];

    auto cdiv = [](int a, int b) { return (a + b - 1) / b; };
    auto GT = [&](int M, int N) { return dim3(cdiv(M, 128), cdiv(N, 128)); };
    auto GT256 = [&](int M, int N) { return dim3(cdiv(M, 256), cdiv(N, 128)); };

    k_init<<<1, 64, 0, stream>>>();
    k_xflat<<<cdiv(N0 * E, 256), 256, 0, stream>>>(x);

    // ---- weight prep ----
    k_reshape<<<cdiv(F * NY, 256), 256, 0, stream>>>(u0_w1, d0_w1, oBD0);
    k_bd1x<<<cdiv(F * NY1, 256), 256, 0, stream>>>(u1_w1, d1_w1, wk, wv);
    k_copymat<<<cdiv(E * F, 256), 256, 0, stream>>>(kv_w, oWX, E, F, F, XSTR);
    k_wprep<<<dim3(8, 8, 4), 256, 0, stream>>>(kv_w, q_w, out_w, wk, wv, wq, proj_w);
    k_prepvec<<<cdiv(3072, 256), 256, 0, stream>>>(kv_b, q_b, out_b, wk, bk, wv, bv, wq, bq, proj_w, proj_b);
    k_cvec<<<cdiv(NY, 256), 256, 0, stream>>>(kv_b);
    // W0Y = kv_w @ BD0 (split-K 4, partials in oYB) -> WX[:, 2560:7680]
    k_wy<<<dim3(4, 40, 4), 256, 0, stream>>>(kv_w);
    k_wyred<<<cdiv(E * NY, 256), 256, 0, stream>>>();
    k_bufy<<<dim3(1, NY / 64, 2), 256, 0, stream>>>(buf0, buf1);
    k_bh<<<dim3(1, E / 64, 2), 256, 0, stream>>>(buf0, wk, bk, wv, bv);

    // ---- X-GEMM: XO = xf @ WX + XB -> [kv0 | KH0 | VH0 | qh | Y0] (K=512, 256-row tiles) ----
    k_tg256<<<GT256(N0, XSTR), 256, 0, stream>>>(oXF, E, oWX, XSTR, oXB, oXO, XSTR, N0, NOFF, E);

    // ---- level 0 (Y0 lives in XO[:, 2560:7680]) ----
    k_huev<<<N0, 160, 0, stream>>>(oB0, oXO + YC0, XSTR, oBUFY0, u0_b1, u0_w2, u0_b2, oEU0, NOFF, N0);
    k_select<<<1, 256, 0, stream>>>(oEU0, oB0, WSZ, oSEL0, oTM0, oEUS0, oB1);
    k_rdat<<<N0, 256, 0, stream>>>(oB0, oXO + YC0, XSTR, oBUFY0, d0_b1, d0_w2, d0_b2, oSEL0, oB1 + 4, oXO, XSTR, buf0, oDAT1);

    // ---- level 1: Y1X = dat1 @ [BD1 | blkdiag(wk,wv)] split-K=2 -> Y1 + DH1K + DH1V ----
    k_y1x<<<dim3(cdiv(N0, 128), NY1 / 128, 2), 256, 0, stream>>>();
    k_y1red<<<2048, 256, 0, stream>>>();
    k_huev<<<N0, 160, 0, stream>>>(oB1, oYB, NY1, oBUFY1, u1_b1, u1_w2, u1_b2, oEU1, oB1 + 4, N0);
    k_select<<<1, 256, 0, stream>>>(oEU1, oB1, WSZ, oSEL1, oTM1, oEUS1, oB2);
    k_rdat<<<N0, 256, 0, stream>>>(oB1, oYB, NY1, oBUFY1, d1_b1, d1_w2, d1_b2, oSEL1, oB2 + 4, oDAT1, F, buf1, oDAT2);

    // ---- DH2 projections (z-batched, 64-tile, M=n2) ----
    k_zgemm<<<dim3(cdiv(N0, 64), E / 64, 2), 256, 0, stream>>>(wk, wv);

    // ---- fused attention + combined output projection + scatter ----
    k_attn<<<N0, 512, 0, stream>>>(bk, bv);
    k_pgemm<<<dim3(cdiv(N0, 64), E / 64), 256, 0, stream>>>(oCTX, E, oWOP, E, oBOP, oY2, E, N0, NOFF, E, E);
    k_scatter<<<cdiv(NBAT * MAXL * E, 256), 256, 0, stream>>>((float*)d_out);
}

// Round 14
// 1345.491 us; speedup vs baseline: 1.0943x; 1.0943x over previous
//
#include <hip/hip_runtime.h>
#include <cstddef>

#define DEVFN __device__ __forceinline__

constexpr int N0   = 2712;             // 768+640+704+600
constexpr int MAXL = 768;
constexpr int NBAT = 4;
constexpr int E    = 512;
constexpr int F    = 1024;
constexpr int HID  = 160;
constexpr int WSZ  = 16;               // window length
constexpr int NY   = 2 * WSZ * HID;    // 5120: [u | d] fused Y width
constexpr int NY1  = 6144;             // level-1: [u|d (5120) | DH1K(512) | DH1V(512)]
constexpr int DH1KC = 5120;
constexpr int DH1VC = 5632;
constexpr int XSTR = 7680;             // XO row: [kv0(1024)|KH0(512)|VH0(512)|qh(512)|Y0(5120)]
constexpr int YC0  = 2560;             // Y0 column base within XO
constexpr size_t NOFF = (size_t)-1;

// ---------------- static device scratch pool (offsets in floats) ----------------
constexpr size_t oXF    = 0;
constexpr size_t oXO    = oXF    + (size_t)N0*E;
constexpr size_t oEU0   = oXO    + (size_t)N0*XSTR;
constexpr size_t oDAT1  = oEU0   + (size_t)N0;
constexpr size_t oEU1   = oDAT1  + (size_t)N0*F;
constexpr size_t oDAT2  = oEU1   + (size_t)N0;
constexpr size_t oBH0K  = oDAT2  + (size_t)N0*F;
constexpr size_t oBH0V  = oBH0K  + (size_t)15*E;
constexpr size_t oDH2K  = oBH0V  + (size_t)15*E;
constexpr size_t oDH2V  = oDH2K  + (size_t)N0*E;
constexpr size_t oCTX   = oDH2V  + (size_t)N0*E;
constexpr size_t oY2    = oCTX   + (size_t)N0*E;
constexpr size_t oEUS0  = oY2    + (size_t)N0*E;
constexpr size_t oEUS1  = oEUS0  + (size_t)N0;
constexpr size_t oSEL0  = oEUS1  + (size_t)N0;
constexpr size_t oTM0   = oSEL0  + (size_t)N0;
constexpr size_t oSEL1  = oTM0   + (size_t)N0;
constexpr size_t oTM1   = oSEL1  + (size_t)N0;
constexpr size_t oB0    = oTM1   + (size_t)N0;
constexpr size_t oB1    = oB0    + 8;
constexpr size_t oB2    = oB1    + 8;
constexpr size_t oWOP   = oB2    + 8;
constexpr size_t oBOP   = oWOP   + (size_t)E*E;
constexpr size_t oWX    = oBOP   + E;              // 512 x 7680
constexpr size_t oXB    = oWX    + (size_t)E*XSTR; // 7680 bias
constexpr size_t oBD0   = oXB    + XSTR;           // F x NY
constexpr size_t oBD1   = oBD0   + (size_t)F*NY;   // F x NY1  ([BD1 | wk-pad | wv-pad])
constexpr size_t oBUFY0 = oBD1   + (size_t)F*NY1;
constexpr size_t oBUFY1 = oBUFY0 + (size_t)15*NY;
constexpr size_t oYB    = oBUFY1 + (size_t)15*NY;  // Y1X (N0 x NY1); also W0Y split-K scratch
constexpr size_t oP1    = oYB    + (size_t)N0*NY1; // Y1X split-K z=1 partial
constexpr size_t oEND   = oP1    + (size_t)N0*NY1;

__device__ float g_pool[oEND];

DEVFN float geluf(float x) {
    return 0.5f * x * (1.0f + erff(x / 1.41421356237309504880f));
}

// ---------------- tiny init ----------------
__global__ void k_init() {
    if (threadIdx.x == 0) {
        int* b = (int*)(g_pool + oB0);
        b[0] = 0; b[1] = 768; b[2] = 1408; b[3] = 2112; b[4] = N0;
    }
}

// ---------------- x (B,768,E) -> x_flat (N0,E) ----------------
__global__ __launch_bounds__(256) void k_xflat(const float* __restrict__ x) {
    int idx = blockIdx.x * 256 + threadIdx.x;
    if (idx >= N0 * E) return;
    int d = idx & (E - 1);
    int g = idx >> 9;
    int s = (g >= 768) + (g >= 1408) + (g >= 2112);
    const int st[4] = {0, 768, 1408, 2112};
    int qp = g - st[s];
    g_pool[oXF + idx] = x[((size_t)s * MAXL + qp) * E + d];
}

// ---------------- w1 (16384,160) pairs -> BD0 (1024, 5120) ----------------
__global__ __launch_bounds__(256) void k_reshape(
    const float* __restrict__ uw, const float* __restrict__ dw, size_t bdOff)
{
    int idx = blockIdx.x * 256 + threadIdx.x;
    if (idx >= F * NY) return;
    int col = idx % NY;
    int f = idx / NY;
    const float* src = (col < NY / 2) ? uw : dw;
    int rem = (col < NY / 2) ? col : col - NY / 2;
    int j = rem / HID, n = rem % HID;
    g_pool[bdOff + idx] = src[((size_t)j * F + f) * HID + n];
}

// ---------------- level-1 B: [BD1 (5120) | wk-pad (512) | wv-pad (512)] (1024 x 6144) ----------------
__global__ __launch_bounds__(256) void k_bd1x(
    const float* __restrict__ uw, const float* __restrict__ dw,
    const float* __restrict__ wk, const float* __restrict__ wv)
{
    int idx = blockIdx.x * 256 + threadIdx.x;
    if (idx >= F * NY1) return;
    int col = idx % NY1;
    int f = idx / NY1;
    float v;
    if (col < NY) {
        const float* src = (col < NY / 2) ? uw : dw;
        int rem = (col < NY / 2) ? col : col - NY / 2;
        int j = rem / HID, n = rem % HID;
        v = src[((size_t)j * F + f) * HID + n];
    } else if (col < DH1VC) {
        int m = col - DH1KC;
        v = (f < E) ? wk[(size_t)f * E + m] : 0.0f;
    } else {
        int m = col - DH1VC;
        v = (f >= E) ? wv[(size_t)(f - E) * E + m] : 0.0f;
    }
    g_pool[oBD1 + idx] = v;
}

// ---------------- kv_w -> WX[:, 0:1024] ----------------
__global__ __launch_bounds__(256) void k_copymat(
    const float* __restrict__ src, size_t dstOff, int rows, int cols, int lds, int ldd)
{
    int idx = blockIdx.x * 256 + threadIdx.x;
    if (idx >= rows * cols) return;
    int r = idx / cols, c = idx % cols;
    g_pool[dstOff + (size_t)r * ldd + c] = src[(size_t)r * lds + c];
}

// ---------------- fused bias prep: XB[0:2560] + BOP[512] ----------------
__global__ __launch_bounds__(256) void k_prepvec(
    const float* __restrict__ kv_b, const float* __restrict__ q_b, const float* __restrict__ out_b,
    const float* __restrict__ wk, const float* __restrict__ bk,
    const float* __restrict__ wv, const float* __restrict__ bv,
    const float* __restrict__ wq, const float* __restrict__ bq,
    const float* __restrict__ proj_w, const float* __restrict__ proj_b)
{
    int idx = blockIdx.x * 256 + threadIdx.x;
    if (idx >= 3072) return;
    if (idx < 1024) { g_pool[oXB + idx] = kv_b[idx]; return; }
    const float* vec; const float* W; const float* add; int n; size_t dst;
    if (idx < 1536)      { n = idx - 1024; vec = kv_b;     W = wk;     add = bk;     dst = oXB + idx; }
    else if (idx < 2048) { n = idx - 1536; vec = kv_b + E; W = wv;     add = bv;     dst = oXB + idx; }
    else if (idx < 2560) { n = idx - 2048; vec = q_b;      W = wq;     add = bq;     dst = oXB + idx; }
    else                 { n = idx - 2560; vec = out_b;    W = proj_w; add = proj_b; dst = oBOP + n; }
    float s = add[n];
    for (int k = 0; k < E; ++k) s = fmaf(vec[k], W[(size_t)k * E + n], s);
    g_pool[dst] = s;
}

// ---------------- cvec = kv_b @ BD0 -> XB[2560:7680] ----------------
__global__ __launch_bounds__(256) void k_cvec(const float* __restrict__ kv_b) {
    int n = blockIdx.x * 256 + threadIdx.x;
    if (n >= NY) return;
    const float* BD = g_pool + oBD0;
    float s = 0.0f;
    for (int k = 0; k < F; ++k) s = fmaf(kv_b[k], BD[(size_t)k * NY + n], s);
    g_pool[oXB + YC0 + n] = s;
}

// ---------------- 64x64 f32 GEMM body (4x4 micro, 256 threads) ----------------
DEVFN void gemm64_body(
    const float* __restrict__ A, int lda,
    const float* __restrict__ B, int ldb,
    const float* __restrict__ bias,
    float* __restrict__ C, int ldc,
    int mval, int row0, int col0, int K, int N)
{
    __shared__ __align__(16) float As[32][68];
    __shared__ __align__(16) float Bs[32][64];

    int tid = threadIdx.x;
    float acc[4][4] = {};
    int tx = tid & 15, ty = tid >> 4;

    for (int k0 = 0; k0 < K; k0 += 32) {
        #pragma unroll
        for (int l = 0; l < 8; ++l) {
            int idx = tid + l * 256;
            int kk = idx & 31, m = idx >> 5;
            int r = row0 + m;
            float v = 0.0f;
            if (r < mval) v = A[(size_t)r * lda + k0 + kk];
            As[kk][m] = v;
        }
        #pragma unroll
        for (int l = 0; l < 8; ++l) {
            int idx = tid + l * 256;
            int n = idx & 63, kk = idx >> 6;
            int col = col0 + n;
            float v = 0.0f;
            if (col < N) v = B[(size_t)(k0 + kk) * ldb + col];
            Bs[kk][n] = v;
        }
        __syncthreads();
        #pragma unroll
        for (int kk = 0; kk < 32; ++kk) {
            float4 a4 = *(const float4*)&As[kk][ty * 4];
            float4 b4 = *(const float4*)&Bs[kk][tx * 4];
            float av[4] = {a4.x, a4.y, a4.z, a4.w};
            float bv[4] = {b4.x, b4.y, b4.z, b4.w};
            #pragma unroll
            for (int i = 0; i < 4; ++i)
                #pragma unroll
                for (int jn = 0; jn < 4; ++jn)
                    acc[i][jn] = fmaf(av[i], bv[jn], acc[i][jn]);
        }
        __syncthreads();
    }

    #pragma unroll
    for (int i = 0; i < 4; ++i) {
        int r = row0 + ty * 4 + i;
        if (r >= mval) continue;
        #pragma unroll
        for (int jn = 0; jn < 4; ++jn) {
            int col = col0 + tx * 4 + jn;
            if (col < N)
                C[(size_t)r * ldc + col] = acc[i][jn] + (bias ? bias[col] : 0.0f);
        }
    }
}

// generic pool-based 64-tile GEMM (y2 projection)
__global__ __launch_bounds__(256) void k_pgemm(
    size_t Aoff, int lda, size_t Boff, int ldb, size_t biasOff,
    size_t Coff, int ldc, int M, size_t mdevOff, int K, int N)
{
    int mval = (mdevOff == NOFF) ? M : *(const int*)(g_pool + mdevOff);
    int row0 = blockIdx.x * 64, col0 = blockIdx.y * 64;
    if (row0 >= mval) return;
    gemm64_body(g_pool + Aoff, lda, g_pool + Boff, ldb,
                (biasOff == NOFF) ? nullptr : g_pool + biasOff,
                g_pool + Coff, ldc, mval, row0, col0, K, N);
}

// z-batched weight-prep: {kv_w_k@wk, kv_w_v@wv, q_w@wq, out_w@proj_w}
__global__ __launch_bounds__(256) void k_wprep(
    const float* __restrict__ kv_w, const float* __restrict__ q_w, const float* __restrict__ out_w,
    const float* __restrict__ wk, const float* __restrict__ wv,
    const float* __restrict__ wq, const float* __restrict__ proj_w)
{
    int z = blockIdx.z;
    const float* A; int lda; const float* B; float* C; int ldc;
    if (z == 0)      { A = kv_w;     lda = F; B = wk;     C = g_pool + oWX + 1024; ldc = XSTR; }
    else if (z == 1) { A = kv_w + E; lda = F; B = wv;     C = g_pool + oWX + 1536; ldc = XSTR; }
    else if (z == 2) { A = q_w;      lda = E; B = wq;     C = g_pool + oWX + 2048; ldc = XSTR; }
    else             { A = out_w;    lda = E; B = proj_w; C = g_pool + oWOP;       ldc = E;    }
    gemm64_body(A, lda, B, E, nullptr, C, ldc, E, blockIdx.x * 64, blockIdx.y * 64, E, E);
}

// z-batched bufY: {buf0@BD0, buf1@BD1 (first 5120 cols of BD1X)}
__global__ __launch_bounds__(256) void k_bufy(
    const float* __restrict__ buf0, const float* __restrict__ buf1)
{
    int z = blockIdx.z;
    const float* A = z ? buf1 : buf0;
    const float* B = g_pool + (z ? oBD1 : oBD0);
    int ldb = z ? NY1 : NY;
    float* C = g_pool + (z ? oBUFY1 : oBUFY0);
    gemm64_body(A, F, B, ldb, nullptr, C, NY, 15, 0, blockIdx.y * 64, F, NY);
}

// z-batched buffer K/V projections: {buf0_k@wk+bk, buf0_v@wv+bv}
__global__ __launch_bounds__(256) void k_bh(
    const float* __restrict__ buf0,
    const float* __restrict__ wk, const float* __restrict__ bk,
    const float* __restrict__ wv, const float* __restrict__ bv)
{
    int z = blockIdx.z;
    const float* A = buf0 + (size_t)z * E;
    const float* B = z ? wv : wk;
    const float* bias = z ? bv : bk;
    float* C = g_pool + (z ? oBH0V : oBH0K);
    gemm64_body(A, F, B, E, bias, C, E, 15, 0, blockIdx.y * 64, E, E);
}

// ---------------- big f32 GEMM: 128x128 tile, 256 threads, 8x8 micro, reg-dbuf ----------------
DEVFN void fma_8x8(const float4& a0, const float4& a1, const float4& b0, const float4& b1,
                   float2 (&acc)[8][4])
{
    float av[8] = {a0.x, a0.y, a0.z, a0.w, a1.x, a1.y, a1.z, a1.w};
    float2 bv[4] = {make_float2(b0.x, b0.y), make_float2(b0.z, b0.w),
                    make_float2(b1.x, b1.y), make_float2(b1.z, b1.w)};
    #pragma unroll
    for (int i = 0; i < 8; ++i) {
        #pragma unroll
        for (int q = 0; q < 4; ++q) {
            acc[i][q].x = fmaf(av[i], bv[q].x, acc[i][q].x);
            acc[i][q].y = fmaf(av[i], bv[q].y, acc[i][q].y);
        }
    }
}

DEVFN void gemm128_body(
    const float* __restrict__ A, int lda,
    const float* __restrict__ B, int ldb,
    const float* __restrict__ bias,
    float* __restrict__ C, int ldc,
    int mval, int row0, int col0, int K)
{
    __shared__ __align__(16) float As[16][132];   // transposed: As[k][m]
    __shared__ __align__(16) float Bs[16][132];

    int tid = threadIdx.x;
    int tx = tid & 15, ty = tid >> 4;             // tx: col quad, ty: row octet
    float2 acc[8][4] = {};

    int ar = tid >> 1, akq = (tid & 1) * 8;       // A staging: row, k-offset
    int bk = tid >> 4, bnq = (tid & 15) * 8;      // B staging: k, n-offset

    for (int k0 = 0; k0 < K; k0 += 16) {
        {
            float4 v0 = make_float4(0.f, 0.f, 0.f, 0.f), v1 = v0;
            int rr = row0 + ar;
            if (rr < mval) {
                v0 = *(const float4*)&A[(size_t)rr * lda + k0 + akq];
                v1 = *(const float4*)&A[(size_t)rr * lda + k0 + akq + 4];
            }
            As[akq + 0][ar] = v0.x; As[akq + 1][ar] = v0.y;
            As[akq + 2][ar] = v0.z; As[akq + 3][ar] = v0.w;
            As[akq + 4][ar] = v1.x; As[akq + 5][ar] = v1.y;
            As[akq + 6][ar] = v1.z; As[akq + 7][ar] = v1.w;
        }
        {
            const float* bp = &B[(size_t)(k0 + bk) * ldb + col0 + bnq];
            *(float4*)&Bs[bk][bnq]     = *(const float4*)&bp[0];
            *(float4*)&Bs[bk][bnq + 4] = *(const float4*)&bp[4];
        }
        __syncthreads();

        float4 a0A = *(const float4*)&As[0][ty * 8];
        float4 a1A = *(const float4*)&As[0][ty * 8 + 4];
        float4 b0A = *(const float4*)&Bs[0][tx * 4];
        float4 b1A = *(const float4*)&Bs[0][64 + tx * 4];
        #pragma unroll
        for (int kk = 0; kk < 16; kk += 2) {
            float4 a0B = *(const float4*)&As[kk + 1][ty * 8];
            float4 a1B = *(const float4*)&As[kk + 1][ty * 8 + 4];
            float4 b0B = *(const float4*)&Bs[kk + 1][tx * 4];
            float4 b1B = *(const float4*)&Bs[kk + 1][64 + tx * 4];
            fma_8x8(a0A, a1A, b0A, b1A, acc);
            if (kk + 2 < 16) {
                a0A = *(const float4*)&As[kk + 2][ty * 8];
                a1A = *(const float4*)&As[kk + 2][ty * 8 + 4];
                b0A = *(const float4*)&Bs[kk + 2][tx * 4];
                b1A = *(const float4*)&Bs[kk + 2][64 + tx * 4];
            }
            fma_8x8(a0B, a1B, b0B, b1B, acc);
        }
        __syncthreads();
    }

    #pragma unroll
    for (int i = 0; i < 8; ++i) {
        int r = row0 + ty * 8 + i;
        if (r >= mval) continue;
        float o0[4], o1[4];
        o0[0] = acc[i][0].x; o0[1] = acc[i][0].y; o0[2] = acc[i][1].x; o0[3] = acc[i][1].y;
        o1[0] = acc[i][2].x; o1[1] = acc[i][2].y; o1[2] = acc[i][3].x; o1[3] = acc[i][3].y;
        if (bias) {
            #pragma unroll
            for (int jn = 0; jn < 4; ++jn) {
                o0[jn] += bias[col0 + tx * 4 + jn];
                o1[jn] += bias[col0 + 64 + tx * 4 + jn];
            }
        }
        *(float4*)&C[(size_t)r * ldc + col0 + tx * 4]      = *(float4*)&o0[0];
        *(float4*)&C[(size_t)r * ldc + col0 + 64 + tx * 4] = *(float4*)&o1[0];
    }
}

__global__ __launch_bounds__(256) void k_tgemm(
    size_t Aoff, int lda, size_t Boff, int ldb, size_t biasOff,
    size_t Coff, int ldc, int M, size_t mdevOff, int K)
{
    int mval = (mdevOff == NOFF) ? M : *(const int*)(g_pool + mdevOff);
    int row0 = blockIdx.x * 128, col0 = blockIdx.y * 128;
    if (row0 >= mval) return;
    gemm128_body(g_pool + Aoff, lda, g_pool + Boff, ldb,
                 (biasOff == NOFF) ? nullptr : g_pool + biasOff,
                 g_pool + Coff, ldc, mval, row0, col0, K);
}

// W0Y = kv_w @ BD0, split-K 4 ways (partials in oYB scratch)
__global__ __launch_bounds__(256) void k_wy(const float* __restrict__ kv_w) {
    int z = blockIdx.z;
    const float* A = kv_w + z * 256;                       // lda=F, K-slice [z*256, z*256+256)
    const float* B = g_pool + oBD0 + (size_t)z * 256 * NY;
    float* C = g_pool + oYB + (size_t)z * E * NY;
    gemm128_body(A, F, B, NY, nullptr, C, NY, E, blockIdx.x * 128, blockIdx.y * 128, 256);
}

__global__ __launch_bounds__(256) void k_wyred() {
    int idx = blockIdx.x * 256 + threadIdx.x;
    if (idx >= E * NY) return;
    int r = idx / NY, c = idx % NY;
    const float* p = g_pool + oYB;
    float s = ((p[idx] + p[(size_t)E * NY + idx]) + p[(size_t)2 * E * NY + idx]) + p[(size_t)3 * E * NY + idx];
    g_pool[oWX + (size_t)r * XSTR + YC0 + c] = s;
}

// Y1X split-K=2: z=0 -> YB (k<512), z=1 -> P1 (k>=512); one dispatch for 2x concurrency
__global__ __launch_bounds__(256) void k_y1x() {
    int mval = *(const int*)(g_pool + oB1 + 4);
    int row0 = blockIdx.x * 128, col0 = blockIdx.y * 128;
    if (row0 >= mval) return;
    int z = blockIdx.z;
    const float* A = g_pool + oDAT1 + (size_t)z * 512;          // lda = F
    const float* B = g_pool + oBD1 + (size_t)z * 512 * NY1;
    float* C = g_pool + (z ? oP1 : oYB);
    gemm128_body(A, F, B, NY1, nullptr, C, NY1, mval, row0, col0, 512);
}

// reduce: YB += P1 (rows < n1), float4 grid-stride; order = lowK + highK
__global__ __launch_bounds__(256) void k_y1red() {
    int mval = *(const int*)(g_pool + oB1 + 4);
    size_t total = (size_t)mval * NY1 / 4;
    float4* yb = (float4*)(g_pool + oYB);
    const float4* p1 = (const float4*)(g_pool + oP1);
    for (size_t i = (size_t)blockIdx.x * 256 + threadIdx.x; i < total; i += (size_t)gridDim.x * 256) {
        float4 a = yb[i], b = p1[i];
        a.x += b.x; a.y += b.y; a.z += b.z; a.w += b.w;
        yb[i] = a;
    }
}

// z-batched DH2 projections (64-tile): {dat2_k@wk, dat2_v@wv}
__global__ __launch_bounds__(256) void k_zgemm(
    const float* __restrict__ wk, const float* __restrict__ wv)
{
    int z = blockIdx.z;
    int mval = *(const int*)(g_pool + oB2 + 4);
    int row0 = blockIdx.x * 64, col0 = blockIdx.y * 64;
    if (row0 >= mval) return;
    const float* A = g_pool + oDAT2 + (size_t)z * E;
    const float* B = z ? wv : wk;
    float* C = g_pool + (z ? oDH2V : oDH2K);
    gemm64_body(A, F, B, E, nullptr, C, E, mval, row0, col0, E, E);
}

// ---------------- fused shift-sum(u) + eu ----------------
__global__ void k_huev(
    size_t boundsOff, size_t yOff, int yStr, size_t bufYOff,
    const float* __restrict__ b1, const float* __restrict__ w2, const float* __restrict__ b2,
    size_t euOff, size_t mdevOff, int M)
{
    int i = blockIdx.x;
    int mval = (mdevOff == NOFF) ? M : *(const int*)(g_pool + mdevOff);
    if (i >= mval) return;
    int n = threadIdx.x;

    __shared__ float t[HID];
    const int* bounds = (const int*)(g_pool + boundsOff);
    int b1i = bounds[1], b2i = bounds[2], b3i = bounds[3];
    int s = (i >= b1i) + (i >= b2i) + (i >= b3i);
    int st = (s == 0) ? 0 : ((s == 1) ? b1i : ((s == 2) ? b2i : b3i));
    int qp = i - st;

    const float* Y = g_pool + yOff;
    const float* bufY = g_pool + bufYOff;

    if (n < HID) {
        float acc = b1[n];
        #pragma unroll
        for (int j = 0; j < WSZ; ++j) {
            int sp = qp - j;
            const float* row = (sp >= 0) ? &Y[(size_t)(i - j) * yStr]
                                         : &bufY[(size_t)(15 + sp) * NY];
            acc += row[j * HID + n];
        }
        t[n] = geluf(acc) * w2[n];
    }
    __syncthreads();
    if (n == 0) {
        float v = b2[0];
        for (int k = 0; k < HID; ++k) v += t[k];
        v = (v > 0.0f) ? v : expm1f(v);
        g_pool[euOff + i] = v + 1.0f;
    }
}

// ---------------- selection scan: serial f32 prefix (bit-exact) + parallel rest ----------------
__global__ __launch_bounds__(256) void k_select(
    size_t euOff, size_t boundsOff, int win,
    size_t selOff, size_t tmOff, size_t euSelOff, size_t boundsNextOff)
{
    __shared__ __align__(16) float se[N0];
    __shared__ __align__(16) float run[N0];
    __shared__ int sFlag[N0];
    __shared__ int sSum[256];
    __shared__ float sCz[NBAT];
    __shared__ int sEc[NBAT];
    __shared__ int sB[5];

    int tid = threadIdx.x;
    const int* bounds = (const int*)(g_pool + boundsOff);
    if (tid < 5) sB[tid] = bounds[tid];
    __syncthreads();
    int N = sB[4];
    for (int i = tid; i < N; i += 256) se[i] = g_pool[euOff + i];
    __syncthreads();

    if (tid == 0) {
        float r = 0.0f;
        int g = 0;
        for (; g + 8 <= N; g += 8) {
            float4 a = *(const float4*)&se[g];
            float4 b4 = *(const float4*)&se[g + 4];
            r += a.x;  run[g]     = r;
            r += a.y;  run[g + 1] = r;
            r += a.z;  run[g + 2] = r;
            r += a.w;  run[g + 3] = r;
            r += b4.x; run[g + 4] = r;
            r += b4.y; run[g + 5] = r;
            r += b4.z; run[g + 6] = r;
            r += b4.w; run[g + 7] = r;
        }
        for (; g < N; ++g) { r += se[g]; run[g] = r; }
        float e0 = run[sB[1] - 1], e1 = run[sB[2] - 1], e2 = run[sB[3] - 1];
        float su0 = e0;
        float su1 = e2 - e1;
        float su2 = run[sB[4] - 1] - e2;
        sCz[0] = 0.0f;
        sCz[1] = su0;
        sCz[2] = su0 + su1;
        sCz[3] = (su0 + su1) + su2;
    }
    __syncthreads();

    for (int g = tid; g < N; g += 256) {
        int seg = (g >= sB[1]) + (g >= sB[2]) + (g >= sB[3]);
        int st = (seg == 0) ? 0 : sB[seg];
        int qp1 = g - st + 1;
        float r2 = run[g] - sCz[seg];
        bool seld = (se[g] > r2 / (float)qp1) || (qp1 <= win);
        sFlag[g] = seld ? 1 : 0;
    }
    __syncthreads();

    int CH = (N + 255) >> 8;
    int lo = tid * CH, hi = min(lo + CH, N);
    {
        int s = 0;
        for (int g = lo; g < hi; ++g) s += sFlag[g];
        sSum[tid] = s;
    }
    __syncthreads();
    if (tid == 0) {
        int acc = 0;
        for (int t = 0; t < 256; ++t) { int v = sSum[t]; sSum[t] = acc; acc += v; }
    }
    __syncthreads();

    int* sel = (int*)(g_pool + selOff);
    int* tm  = (int*)(g_pool + tmOff);
    float* eus = g_pool + euSelOff;
    int* bn  = (int*)(g_pool + boundsNextOff);

    int csel0 = sFlag[0];
    {
        int csel = sSum[tid];
        for (int g = lo; g < hi; ++g) {
            csel += sFlag[g];
            tm[g] = csel - csel0;
            if (sFlag[g]) { sel[csel - 1] = g; eus[csel - 1] = se[g]; }
            #pragma unroll
            for (int s = 0; s < NBAT; ++s)
                if (g == sB[s + 1] - 1) sEc[s] = csel;
        }
    }
    __syncthreads();
    if (tid == 0) {
        bn[0] = 0; bn[1] = sEc[0]; bn[2] = sEc[1]; bn[3] = sEc[2]; bn[4] = sEc[3];
    }
}

// ---------------- fused shift-sum(d) + r-softmax + dat (float4 f-loop) ----------------
__global__ __launch_bounds__(256) void k_rdat(
    size_t boundsOff, size_t yOff, int yStr, size_t bufYOff,
    const float* __restrict__ b1, const float* __restrict__ w2, const float* __restrict__ b2,
    size_t selOff, size_t mdevOff,
    size_t srcOff, int srcStr, const float* __restrict__ buf,
    size_t datOff)
{
    int i = blockIdx.x;
    if (i >= *(const int*)(g_pool + mdevOff)) return;
    const float* src = g_pool + srcOff;
    const int* bounds = (const int*)(g_pool + boundsOff);
    const int* sel = (const int*)(g_pool + selOff);
    float* dat = g_pool + datOff;

    __shared__ float gh[HID];
    __shared__ float sv[WSZ];
    __shared__ float r[WSZ];
    __shared__ int sG, sQp;

    int tid = threadIdx.x;
    if (tid == 0) {
        int g = sel[i];
        int b1i = bounds[1], b2i = bounds[2], b3i = bounds[3];
        int s = (g >= b1i) + (g >= b2i) + (g >= b3i);
        int st = (s == 0) ? 0 : ((s == 1) ? b1i : ((s == 2) ? b2i : b3i));
        sG = g; sQp = g - st;
    }
    __syncthreads();
    int g = sG, qp = sQp;

    if (tid < HID) {
        const float* Y = g_pool + yOff;
        const float* bufY = g_pool + bufYOff;
        float acc = b1[tid];
        #pragma unroll
        for (int j = 0; j < WSZ; ++j) {
            int sp = qp - j;
            const float* row = (sp >= 0) ? &Y[(size_t)(g - j) * yStr]
                                         : &bufY[(size_t)(15 + sp) * NY];
            acc += row[NY / 2 + j * HID + tid];
        }
        gh[tid] = geluf(acc);
    }
    __syncthreads();
    if (tid < WSZ) {
        float acc = 0.0f;
        for (int k = 0; k < HID; ++k) acc += gh[k] * w2[k * WSZ + tid];
        sv[tid] = acc + b2[tid];
    }
    __syncthreads();
    if (tid == 0) {
        float m = sv[0];
        for (int t = 1; t < WSZ; ++t) m = fmaxf(m, sv[t]);
        float sum = 0.0f;
        for (int t = 0; t < WSZ; ++t) { float e = expf(sv[t] - m); r[t] = e; sum += e; }
        for (int t = 0; t < WSZ; ++t) r[t] = r[t] / sum;
    }
    __syncthreads();
    {
        int f0 = tid * 4;            // 256 threads x 4 = 1024 = F
        float4 acc = make_float4(0.f, 0.f, 0.f, 0.f);
        #pragma unroll
        for (int j = 0; j < WSZ; ++j) {
            int sp = qp - j;
            const float* row = (sp >= 0) ? &src[(size_t)(g - j) * srcStr]
                                         : &buf[(size_t)(15 + sp) * F];
            float4 v = *(const float4*)&row[f0];
            float rj = r[j];
            acc.x = fmaf(rj, v.x, acc.x);
            acc.y = fmaf(rj, v.y, acc.y);
            acc.z = fmaf(rj, v.z, acc.z);
            acc.w = fmaf(rj, v.w, acc.w);
        }
        *(float4*)&dat[(size_t)i * F + f0] = acc;
    }
}

// ---------------- fused attention over 48 gathered kv slots ----------------
__global__ __launch_bounds__(512) void k_attn(
    const float* __restrict__ bk, const float* __restrict__ bv)
{
    int g = blockIdx.x;
    const float* XO   = g_pool + oXO;
    const float* BH0k = g_pool + oBH0K;
    const float* BH0v = g_pool + oBH0V;
    const float* Y1X  = g_pool + oYB;     // DH1K/DH1V live at cols 5120/5632, stride NY1
    const float* DH2k = g_pool + oDH2K;
    const float* DH2v = g_pool + oDH2V;
    const float* eus0 = g_pool + oEUS0;
    const float* eus1 = g_pool + oEUS1;
    const int* tm0 = (const int*)(g_pool + oTM0);
    const int* tm1 = (const int*)(g_pool + oTM1);
    const int* bounds1 = (const int*)(g_pool + oB1);
    const int* bounds2 = (const int*)(g_pool + oB2);

    __shared__ const float* sK[48];
    __shared__ const float* sV[48];
    __shared__ float sScale[48];
    __shared__ __align__(16) float sQ[E], sBk[E], sBv[E];
    __shared__ float sc[48][8];

    int tid = threadIdx.x;
    sQ[tid]  = XO[(size_t)g * XSTR + 2048 + tid];
    sBk[tid] = bk[tid];
    sBv[tid] = bv[tid];

    if (tid < 48) {
        int s = tid;
        const float *pK = nullptr, *pV = nullptr;
        float scl = 0.0f;
        if (s < 16) {
            int s0 = (g >= 768) + (g >= 1408) + (g >= 2112);
            const int st0[4] = {0, 768, 1408, 2112};
            int sp = (g - st0[s0]) - s;
            if (sp >= 0) { pK = XO + (size_t)(g - s) * XSTR + 1024; pV = XO + (size_t)(g - s) * XSTR + 1536; }
            else         { pK = BH0k + (size_t)(15 + sp) * E; pV = BH0v + (size_t)(15 + sp) * E; }
            scl = 1.0f;
        } else if (s < 32) {
            int j = s - 16;
            int i1 = tm0[g];
            int b1 = bounds1[1], b2 = bounds1[2], b3 = bounds1[3];
            int sg = (i1 >= b1) + (i1 >= b2) + (i1 >= b3);
            int st = (sg == 0) ? 0 : ((sg == 1) ? b1 : ((sg == 2) ? b2 : b3));
            int sp = (i1 - st) - j;
            if (sp >= 0) {
                pK = Y1X + (size_t)(i1 - j) * NY1 + DH1KC;
                pV = Y1X + (size_t)(i1 - j) * NY1 + DH1VC;
                scl = eus0[i1 - j];
            }
        } else {
            int j = s - 32;
            int i1 = tm0[g];
            int i2 = tm1[i1];
            int b1 = bounds2[1], b2 = bounds2[2], b3 = bounds2[3];
            int sg = (i2 >= b1) + (i2 >= b2) + (i2 >= b3);
            int st = (sg == 0) ? 0 : ((sg == 1) ? b1 : ((sg == 2) ? b2 : b3));
            int sp = (i2 - st) - j;
            if (sp >= 0) { pK = DH2k + (size_t)(i2 - j) * E; pV = DH2v + (size_t)(i2 - j) * E; scl = eus1[i2 - j]; }
        }
        sK[s] = pK; sV[s] = pV; sScale[s] = scl;
    }
    __syncthreads();

    if (tid < 384) {
        int s = tid >> 3, h = tid & 7;
        const float* bp = sK[s];
        float scl = sScale[s];
        float acc = 0.0f;
        int d0 = h * 64;
        if (s < 16) {
            for (int d = 0; d < 64; d += 4) {
                float4 qv = *(const float4*)&sQ[d0 + d];
                float4 kv4 = *(const float4*)&bp[d0 + d];
                acc += qv.x * kv4.x; acc += qv.y * kv4.y;
                acc += qv.z * kv4.z; acc += qv.w * kv4.w;
            }
        } else if (bp) {
            for (int d = 0; d < 64; d += 4) {
                float4 qv = *(const float4*)&sQ[d0 + d];
                float4 kv4 = *(const float4*)&bp[d0 + d];
                float4 bb = *(const float4*)&sBk[d0 + d];
                acc += qv.x * (bb.x + scl * kv4.x); acc += qv.y * (bb.y + scl * kv4.y);
                acc += qv.z * (bb.z + scl * kv4.z); acc += qv.w * (bb.w + scl * kv4.w);
            }
        } else {
            for (int d = 0; d < 64; d += 4) {
                float4 qv = *(const float4*)&sQ[d0 + d];
                float4 bb = *(const float4*)&sBk[d0 + d];
                acc += qv.x * bb.x; acc += qv.y * bb.y;
                acc += qv.z * bb.z; acc += qv.w * bb.w;
            }
        }
        sc[s][h] = acc * 0.125f;   // / sqrt(64)
    }
    __syncthreads();

    if (tid < 8) {
        int h = tid;
        float m = sc[0][h];
        for (int s = 1; s < 48; ++s) m = fmaxf(m, sc[s][h]);
        float sum = 0.0f;
        for (int s = 0; s < 48; ++s) { float e = expf(sc[s][h] - m); sc[s][h] = e; sum += e; }
        for (int s = 0; s < 48; ++s) sc[s][h] = sc[s][h] / sum;
    }
    __syncthreads();

    {
        int d = tid, h = d >> 6;
        float acc = 0.0f;
        for (int s = 0; s < 48; ++s) {
            const float* bp = sV[s];
            float vv;
            if (s < 16) vv = bp[d];
            else        vv = sBv[d] + (bp ? sScale[s] * bp[d] : 0.0f);
            acc = fmaf(sc[s][h], vv, acc);
        }
        g_pool[oCTX + (size_t)g * E + d] = acc;
    }
}

// ---------------- y2 -> out (B, 768, E) with zero padding ----------------
__global__ __launch_bounds__(256) void k_scatter(float* __restrict__ out) {
    int idx = blockIdx.x * 256 + threadIdx.x;
    if (idx >= NBAT * MAXL * E) return;
    int d = idx & (E - 1);
    int rest = idx >> 9;
    int p = rest % MAXL, bb = rest / MAXL;
    const int st[4] = {0, 768, 1408, 2112};
    const int ln[4] = {768, 640, 704, 600};
    out[idx] = (p < ln[bb]) ? g_pool[oY2 + (size_t)(st[bb] + p) * E + d] : 0.0f;
}

// ================================================================================
extern "C" void kernel_launch(void* const* d_in, const int* in_sizes, int n_in,
                              void* d_out, int out_size, void* d_ws, size_t ws_size,
                              hipStream_t stream)
{
    (void)in_sizes; (void)n_in; (void)d_ws; (void)ws_size; (void)out_size;

    const float* x      = (const float*)d_in[0];
    const float* kv_w   = (const float*)d_in[2];
    const float* kv_b   = (const float*)d_in[3];
    const float* q_w    = (const float*)d_in[4];
    const float* q_b    = (const float*)d_in[5];
    const float* proj_w = (const float*)d_in[6];
    const float* proj_b = (const float*)d_in[7];
    const float* buf0   = (const float*)d_in[8];
    const float* buf1   = (const float*)d_in[9];
    const float* d0_w1  = (const float*)d_in[11];
    const float* d0_b1  = (const float*)d_in[12];
    const float* d0_w2  = (const float*)d_in[13];
    const float* d0_b2  = (const float*)d_in[14];
    const float* u0_w1  = (const float*)d_in[15];
    const float* u0_b1  = (const float*)d_in[16];
    const float* u0_w2  = (const float*)d_in[17];
    const float* u0_b2  = (const float*)d_in[18];
    const float* d1_w1  = (const float*)d_in[19];
    const float* d1_b1  = (const float*)d_in[20];
    const float* d1_w2  = (const float*)d_in[21];
    const float* d1_b2  = (const float*)d_in[22];
    const float* u1_w1  = (const float*)d_in[23];
    const float* u1_b1  = (const float*)d_in[24];
    const float* u1_w2  = (const float*)d_in[25];
    const float* u1_b2  = (const float*)d_in[26];
    const float* wq     = (const float*)d_in[27];
    const float* bq     = (const float*)d_in[28];
    const float* wk     = (const float*)d_in[29];
    const float* bk     = (const float*)d_in[30];
    const float* wv     = (const float*)d_in[31];
    const float* bv     = (const float*)d_in[32];
    const float* out_w  = (const float*)d_in[33];
    const float* out_b  = (const float*)d_in[34];

    auto cdiv = [](int a, int b) { return (a + b - 1) / b; };
    auto GT = [&](int M, int N) { return dim3(cdiv(M, 128), cdiv(N, 128)); };

    k_init<<<1, 64, 0, stream>>>();
    k_xflat<<<cdiv(N0 * E, 256), 256, 0, stream>>>(x);

    // ---- weight prep ----
    k_reshape<<<cdiv(F * NY, 256), 256, 0, stream>>>(u0_w1, d0_w1, oBD0);
    k_bd1x<<<cdiv(F * NY1, 256), 256, 0, stream>>>(u1_w1, d1_w1, wk, wv);
    k_copymat<<<cdiv(E * F, 256), 256, 0, stream>>>(kv_w, oWX, E, F, F, XSTR);
    k_wprep<<<dim3(8, 8, 4), 256, 0, stream>>>(kv_w, q_w, out_w, wk, wv, wq, proj_w);
    k_prepvec<<<cdiv(3072, 256), 256, 0, stream>>>(kv_b, q_b, out_b, wk, bk, wv, bv, wq, bq, proj_w, proj_b);
    k_cvec<<<cdiv(NY, 256), 256, 0, stream>>>(kv_b);
    // W0Y = kv_w @ BD0 (split-K 4, partials in oYB) -> WX[:, 2560:7680]
    k_wy<<<dim3(4, 40, 4), 256, 0, stream>>>(kv_w);
    k_wyred<<<cdiv(E * NY, 256), 256, 0, stream>>>();
    k_bufy<<<dim3(1, NY / 64, 2), 256, 0, stream>>>(buf0, buf1);
    k_bh<<<dim3(1, E / 64, 2), 256, 0, stream>>>(buf0, wk, bk, wv, bv);

    // ---- X-GEMM: XO = xf @ WX + XB -> [kv0 | KH0 | VH0 | qh | Y0] (K=512, 128-tile) ----
    k_tgemm<<<GT(N0, XSTR), 256, 0, stream>>>(oXF, E, oWX, XSTR, oXB, oXO, XSTR, N0, NOFF, E);

    // ---- level 0 (Y0 lives in XO[:, 2560:7680]) ----
    k_huev<<<N0, 160, 0, stream>>>(oB0, oXO + YC0, XSTR, oBUFY0, u0_b1, u0_w2, u0_b2, oEU0, NOFF, N0);
    k_select<<<1, 256, 0, stream>>>(oEU0, oB0, WSZ, oSEL0, oTM0, oEUS0, oB1);
    k_rdat<<<N0, 256, 0, stream>>>(oB0, oXO + YC0, XSTR, oBUFY0, d0_b1, d0_w2, d0_b2, oSEL0, oB1 + 4, oXO, XSTR, buf0, oDAT1);

    // ---- level 1: Y1X = dat1 @ [BD1 | blkdiag(wk,wv)] split-K=2 -> Y1 + DH1K + DH1V ----
    k_y1x<<<dim3(cdiv(N0, 128), NY1 / 128, 2), 256, 0, stream>>>();
    k_y1red<<<2048, 256, 0, stream>>>();
    k_huev<<<N0, 160, 0, stream>>>(oB1, oYB, NY1, oBUFY1, u1_b1, u1_w2, u1_b2, oEU1, oB1 + 4, N0);
    k_select<<<1, 256, 0, stream>>>(oEU1, oB1, WSZ, oSEL1, oTM1, oEUS1, oB2);
    k_rdat<<<N0, 256, 0, stream>>>(oB1, oYB, NY1, oBUFY1, d1_b1, d1_w2, d1_b2, oSEL1, oB2 + 4, oDAT1, F, buf1, oDAT2);

    // ---- DH2 projections (z-batched, 64-tile, M=n2) ----
    k_zgemm<<<dim3(cdiv(N0, 64), E / 64, 2), 256, 0, stream>>>(wk, wv);

    // ---- fused attention + combined output projection + scatter ----
    k_attn<<<N0, 512, 0, stream>>>(bk, bv);
    k_pgemm<<<dim3(cdiv(N0, 64), E / 64), 256, 0, stream>>>(oCTX, E, oWOP, E, oBOP, oY2, E, N0, NOFF, E, E);
    k_scatter<<<cdiv(NBAT * MAXL * E, 256), 256, 0, stream>>>((float*)d_out);
}